// Round 1
// baseline (553.545 us; speedup 1.0000x reference)
//
#include <hip/hip_runtime.h>

typedef __attribute__((ext_vector_type(8))) short bf16x8;
typedef __attribute__((ext_vector_type(4))) float f32x4;

__device__ __forceinline__ unsigned short f2bf(float x) {
  union { float f; unsigned u; } v; v.f = x;
  return (unsigned short)((v.u + 0x7fffu + ((v.u >> 16) & 1u)) >> 16);
}
__device__ __forceinline__ float bf2f(unsigned short h) {
  union { unsigned u; float f; } v; v.u = ((unsigned)h) << 16; return v.f;
}

// ---------------- degree histogram ----------------
__global__ void hist_k(const int* __restrict__ dst, int* __restrict__ cnt, int E) {
  int e = blockIdx.x * 256 + threadIdx.x;
  if (e < E) atomicAdd(&cnt[dst[e]], 1);
}

__global__ void dinv_k(const int* __restrict__ cnt, float* __restrict__ dinv, int N) {
  int i = blockIdx.x * 256 + threadIdx.x;
  if (i < N) dinv[i] = rsqrtf((float)(cnt[i] + 1));  // +1 self-loop
}

// ---------------- exclusive scan (3 kernels) ----------------
__global__ void scanA_k(const int* __restrict__ cnt, int* __restrict__ out,
                        int* __restrict__ blkSums, int N) {
  __shared__ int sd[256];
  int t = threadIdx.x;
  int i0 = blockIdx.x * 1024 + t * 4;
  int v0 = 0, v1 = 0, v2 = 0, v3 = 0;
  if (i0 + 0 < N) v0 = cnt[i0 + 0];
  if (i0 + 1 < N) v1 = cnt[i0 + 1];
  if (i0 + 2 < N) v2 = cnt[i0 + 2];
  if (i0 + 3 < N) v3 = cnt[i0 + 3];
  int tsum = v0 + v1 + v2 + v3;
  sd[t] = tsum; __syncthreads();
  for (int off = 1; off < 256; off <<= 1) {
    int x = (t >= off) ? sd[t - off] : 0;
    __syncthreads();
    sd[t] += x;
    __syncthreads();
  }
  int excl = sd[t] - tsum;  // exclusive prefix within block
  if (i0 + 0 < N) out[i0 + 0] = excl;
  if (i0 + 1 < N) out[i0 + 1] = excl + v0;
  if (i0 + 2 < N) out[i0 + 2] = excl + v0 + v1;
  if (i0 + 3 < N) out[i0 + 3] = excl + v0 + v1 + v2;
  if (t == 255) blkSums[blockIdx.x] = sd[255];
}

__global__ void scanB_k(const int* __restrict__ blkSums, int* __restrict__ blkOff, int nb) {
  __shared__ int sd[1024];
  int t = threadIdx.x;
  int v = (t < nb) ? blkSums[t] : 0;
  sd[t] = v; __syncthreads();
  for (int off = 1; off < 1024; off <<= 1) {
    int x = (t >= off) ? sd[t - off] : 0;
    __syncthreads();
    sd[t] += x;
    __syncthreads();
  }
  if (t < nb) blkOff[t] = sd[t] - v;
}

__global__ void scanC_k(int* __restrict__ row_start, int* __restrict__ fill,
                        const int* __restrict__ blkOff, int N, int E) {
  int i = blockIdx.x * 256 + threadIdx.x;
  if (i < N) {
    int v = row_start[i] + blkOff[i >> 10];
    row_start[i] = v;
    fill[i] = v;
  }
  if (i == 0) row_start[N] = E;
}

// ---------------- CSR scatter ----------------
__global__ void scatter_k(const int* __restrict__ src, const int* __restrict__ dst,
                          int* __restrict__ fill, int* __restrict__ csr, int E) {
  int e = blockIdx.x * 256 + threadIdx.x;
  if (e < E) {
    int d = dst[e];
    int pos = atomicAdd(&fill[d], 1);
    csr[pos] = src[e];
  }
}

// ---------------- GEMM: [M,128] @ [128,NCOL] via 16x16x32 bf16 MFMA ----------------
// A row-major (fp32 or bf16), W fp32 row-major [128][NCOL] staged transposed->LDS as bf16.
// Out: bf16 [M,NCOL] (no bias) or fp32 [M,NCOL] (+bias).
template <int NCOL, bool INF32, bool OUTF32>
__global__ __launch_bounds__(256) void gemm_k(const void* __restrict__ Ap,
                                              const float* __restrict__ W,
                                              const float* __restrict__ bias,
                                              void* __restrict__ Cp, int M) {
  __shared__ __align__(16) unsigned short Ws[NCOL * 136];  // [n][k], k-pad to 136 (16B rows)
  int tid = threadIdx.x;
  for (int e = tid; e < 128 * NCOL; e += 256) {
    int k = e / NCOL, n = e % NCOL;
    Ws[n * 136 + k] = f2bf(W[e]);
  }
  __syncthreads();

  int wave = tid >> 6, lane = tid & 63;
  int q = lane >> 4, r = lane & 15;
  const int NT = NCOL / 16;
  int ntile = M >> 4;  // M=100000 -> 6250 exact
  for (int tile = blockIdx.x * 4 + wave; tile < ntile; tile += gridDim.x * 4) {
    int row = tile * 16 + r;
    bf16x8 a[4];
    if (INF32) {
      const float* A = (const float*)Ap + (size_t)row * 128 + q * 8;
#pragma unroll
      for (int kk = 0; kk < 4; kk++) {
        const float4* p = (const float4*)(A + kk * 32);
        float4 f0 = p[0], f1 = p[1];
        bf16x8 t;
        t[0] = (short)f2bf(f0.x); t[1] = (short)f2bf(f0.y);
        t[2] = (short)f2bf(f0.z); t[3] = (short)f2bf(f0.w);
        t[4] = (short)f2bf(f1.x); t[5] = (short)f2bf(f1.y);
        t[6] = (short)f2bf(f1.z); t[7] = (short)f2bf(f1.w);
        a[kk] = t;
      }
    } else {
      const unsigned short* A = (const unsigned short*)Ap + (size_t)row * 128 + q * 8;
#pragma unroll
      for (int kk = 0; kk < 4; kk++) a[kk] = *(const bf16x8*)(A + kk * 32);
    }
    f32x4 acc[NT];
#pragma unroll
    for (int nt = 0; nt < NT; nt++) { acc[nt][0] = 0.f; acc[nt][1] = 0.f; acc[nt][2] = 0.f; acc[nt][3] = 0.f; }
#pragma unroll
    for (int kk = 0; kk < 4; kk++) {
#pragma unroll
      for (int nt = 0; nt < NT; nt++) {
        bf16x8 b = *(const bf16x8*)&Ws[(nt * 16 + r) * 136 + kk * 32 + q * 8];
        acc[nt] = __builtin_amdgcn_mfma_f32_16x16x32_bf16(a[kk], b, acc[nt], 0, 0, 0);
      }
    }
    // D: row = q*4+rr, col = nt*16+r
#pragma unroll
    for (int nt = 0; nt < NT; nt++) {
#pragma unroll
      for (int rr = 0; rr < 4; rr++) {
        int orow = tile * 16 + q * 4 + rr;
        int ocol = nt * 16 + r;
        if (OUTF32)
          ((float*)Cp)[(size_t)orow * NCOL + ocol] = acc[nt][rr] + bias[ocol];
        else
          ((unsigned short*)Cp)[(size_t)orow * NCOL + ocol] = f2bf(acc[nt][rr]);
      }
    }
  }
}

// ---------------- aggregation: one wave per node, lane = 2 features ----------------
// out[i] = relu( (h[i]*dinv[i] + sum_{s in in(i)} h[s]*dinv[s]) * dinv[i] + bias )  (bf16)
__global__ __launch_bounds__(256) void agg_k(const unsigned* __restrict__ h,
                                             const float* __restrict__ dinv,
                                             const int* __restrict__ row_start,
                                             const int* __restrict__ csr,
                                             const float* __restrict__ bias,
                                             unsigned* __restrict__ out, int N) {
  int lane = threadIdx.x & 63;
  int node = (blockIdx.x * 256 + threadIdx.x) >> 6;
  if (node >= N) return;
  float di = dinv[node];
  unsigned hv = h[(size_t)node * 64 + lane];
  float ax = bf2f((unsigned short)(hv & 0xffffu)) * di;
  float ay = bf2f((unsigned short)(hv >> 16)) * di;
  int beg = row_start[node], end = row_start[node + 1];
  for (int base = beg; base < end; base += 64) {
    int m = end - base; if (m > 64) m = 64;
    int s = 0; float wv = 0.f;
    if (lane < m) { s = csr[base + lane]; wv = dinv[s]; }
    for (int j = 0; j < m; ++j) {
      int sj = __shfl(s, j);
      float wj = __shfl(wv, j);
      unsigned hj = h[(size_t)sj * 64 + lane];
      ax += bf2f((unsigned short)(hj & 0xffffu)) * wj;
      ay += bf2f((unsigned short)(hj >> 16)) * wj;
    }
  }
  float r0 = ax * di + bias[lane * 2];     if (r0 < 0.f) r0 = 0.f;
  float r1 = ay * di + bias[lane * 2 + 1]; if (r1 < 0.f) r1 = 0.f;
  out[(size_t)node * 64 + lane] = (unsigned)f2bf(r0) | ((unsigned)f2bf(r1) << 16);
}

extern "C" void kernel_launch(void* const* d_in, const int* in_sizes, int n_in,
                              void* d_out, int out_size, void* d_ws, size_t ws_size,
                              hipStream_t stream) {
  const float* x  = (const float*)d_in[0];
  const int* ei   = (const int*)d_in[1];
  const float* W1 = (const float*)d_in[2];
  const float* b1 = (const float*)d_in[3];
  const float* W2 = (const float*)d_in[4];
  const float* b2 = (const float*)d_in[5];
  const float* fcW = (const float*)d_in[6];
  const float* fcb = (const float*)d_in[7];
  float* out = (float*)d_out;

  int N = in_sizes[0] / 128;  // 100000
  int E = in_sizes[1] / 2;    // 1600000
  const int* src = ei;
  const int* dst = ei + E;

  char* w = (char*)d_ws;
  auto alloc = [&](size_t b) { char* p = w; w += (b + 255) & ~(size_t)255; return p; };
  int*   cnt       = (int*)alloc((size_t)N * 4);
  float* dinv      = (float*)alloc((size_t)N * 4);
  int*   row_start = (int*)alloc((size_t)(N + 1) * 4);
  int*   fill      = (int*)alloc((size_t)N * 4);
  int*   blkSums   = (int*)alloc(4096);
  int*   blkOff    = (int*)alloc(4096);
  int*   csr       = (int*)alloc((size_t)E * 4);
  unsigned short* bufA = (unsigned short*)alloc((size_t)N * 128 * 2);
  unsigned short* bufB = (unsigned short*)alloc((size_t)N * 128 * 2);

  hipMemsetAsync(cnt, 0, (size_t)N * 4, stream);

  int eb = (E + 255) / 256;
  int nb256 = (N + 255) / 256;
  int nb = (N + 1023) / 1024;

  hist_k<<<eb, 256, 0, stream>>>(dst, cnt, E);
  dinv_k<<<nb256, 256, 0, stream>>>(cnt, dinv, N);
  scanA_k<<<nb, 256, 0, stream>>>(cnt, row_start, blkSums, N);
  scanB_k<<<1, 1024, 0, stream>>>(blkSums, blkOff, nb);
  scanC_k<<<nb256, 256, 0, stream>>>(row_start, fill, blkOff, N, E);
  scatter_k<<<eb, 256, 0, stream>>>(src, dst, fill, csr, E);

  // layer 1: h1 = x @ W1   (fp32 in, bf16 out)
  gemm_k<128, true, false><<<512, 256, 0, stream>>>((const void*)x, W1, nullptr, (void*)bufA, N);
  // agg1: a1 = relu(norm-agg(h1) + b1)  (bf16)
  agg_k<<<(N + 3) / 4, 256, 0, stream>>>((const unsigned*)bufA, dinv, row_start, csr, b1,
                                         (unsigned*)bufB, N);
  // layer 2: h2 = a1 @ W2
  gemm_k<128, false, false><<<512, 256, 0, stream>>>((const void*)bufB, W2, nullptr, (void*)bufA, N);
  // agg2: a2 = relu(norm-agg(h2) + b2)
  agg_k<<<(N + 3) / 4, 256, 0, stream>>>((const unsigned*)bufA, dinv, row_start, csr, b2,
                                         (unsigned*)bufB, N);
  // fc: out = a2 @ fcW + fcb  (fp32 out)
  gemm_k<64, false, true><<<512, 256, 0, stream>>>((const void*)bufB, fcW, fcb, (void*)out, N);
}